// Round 13
// baseline (38.384 us; speedup 1.0000x reference)
//
#include <hip/hip_runtime.h>
#include <cstdint>
#include <cstddef>

static constexpr int HW_ = 16384;  // h*w
static constexpr int NB_ = 32;     // batch
static constexpr int NN_ = 64;     // n
static constexpr int BK_ = 128;    // k per staged LDS tile (r13: granule probe)

typedef short bfrag  __attribute__((ext_vector_type(8)));  // 8 bf16 (4 VGPRs)
typedef float f32x4  __attribute__((ext_vector_type(4)));  // MFMA accumulator

// fp32 -> bf16, round-to-nearest-even
__device__ __forceinline__ unsigned short f2bf_rne(float x) {
    unsigned u = __builtin_bit_cast(unsigned, x);
    return (unsigned short)((u + 0x7FFFu + ((u >> 16) & 1u)) >> 16);
}

// XOR-swizzled bf16-element index in a row-major [64][BK_=128] bf16 tile
// (256 B rows). byte ^= (row&7)<<4: fragment reads at fixed k hit 16 rows ->
// spread across 8 16B slots (2-way, free). Same involution on write+read;
// preserves 8B/16B alignment (flips only byte-bit 4).
__device__ __forceinline__ int swz(int row, int k) {
    int byte = (row << 8) + (k << 1);
    byte ^= (row & 7) << 4;
    return byte >> 1;
}

// r13 granule probe: BK=128 with 512 threads. Per-thread staging burst is
// IDENTICAL to r8 (4 float4 loads, 4 ds_writes) — r9's BK=128 failure
// confounded granule with per-thread burst doubling. Here only the per-row
// read granule changes: 256B -> 512B contiguous per wave per tile.
// Proven r8 order kept: stage_load(next) -> compute(cur) -> stage_write(next).
__global__ __launch_bounds__(512) void gram_kernel(const float* __restrict__ masks,
                                                   float* __restrict__ gram_part,
                                                   float* __restrict__ s_part,
                                                   unsigned int* __restrict__ counter,
                                                   int NC, int KC) {
    // zero loss2's sync counter (stream-ordered; kills the memset dispatch)
    if (blockIdx.x == 0 && threadIdx.x == 0) *counter = 0u;

    __shared__ __align__(16) unsigned short lds[2][NN_ * BK_];  // 2 x 16 KiB bf16
    const int bx = blockIdx.x;
    const int b  = bx / NC;
    const int c  = bx - b * NC;
    const int t  = threadIdx.x;        // 512 threads = 8 waves
    const int l  = t & 63;
    const int w  = t >> 6;             // wave 0..7
    const int wr = w >> 1;             // row stripe: rows [16wr, 16wr+16)
    const int wc = w & 1;              // col half: col blocks 2wc, 2wc+1
    const int lrow = t >> 5;           // staging row base 0..15
    const int lk4  = t & 31;           // staging float4 index along k (32/row)
    const float* mb = masks + (size_t)b * (NN_ * HW_) + (size_t)c * KC;
    const int NT = KC / BK_;           // 8 at NC=16

    f32x4 acc[2];
    acc[0] = (f32x4){0.f, 0.f, 0.f, 0.f};
    acc[1] = (f32x4){0.f, 0.f, 0.f, 0.f};
    float sreg[4] = {0.f, 0.f, 0.f, 0.f};
    float4 ld[4];                      // same per-thread burst as r8

    auto stage_load = [&](int tt) {
        const float* src = mb + tt * BK_ + lk4 * 4;
#pragma unroll
        for (int p = 0; p < 4; ++p)
            ld[p] = *reinterpret_cast<const float4*>(src + (size_t)(lrow + 16 * p) * HW_);
    };
    auto stage_write = [&](unsigned short* buf) {
#pragma unroll
        for (int p = 0; p < 4; ++p) {
            const float m0 = fmaxf(0.f, (ld[p].x + 1.f) * 0.5f);
            const float m1 = fmaxf(0.f, (ld[p].y + 1.f) * 0.5f);
            const float m2 = fmaxf(0.f, (ld[p].z + 1.f) * 0.5f);
            const float m3 = fmaxf(0.f, (ld[p].w + 1.f) * 0.5f);
            sreg[p] += (m0 + m1) + (m2 + m3);
            const ushort4 pk = make_ushort4(f2bf_rne(m0), f2bf_rne(m1),
                                            f2bf_rne(m2), f2bf_rne(m3));
            *reinterpret_cast<ushort4*>(&buf[swz(lrow + 16 * p, lk4 * 4)]) = pk;
        }
    };
    auto compute = [&](const unsigned short* buf) {
#pragma unroll
        for (int ks = 0; ks < BK_; ks += 32) {
            const int kb = ks + ((l >> 4) << 3);
            const bfrag a = *reinterpret_cast<const bfrag*>(&buf[swz((wr << 4) + (l & 15), kb)]);
#pragma unroll
            for (int cb = 0; cb < 2; ++cb) {
                const int jb = 2 * wc + cb;   // global 16-col block
                const bfrag bb = *reinterpret_cast<const bfrag*>(&buf[swz((jb << 4) + (l & 15), kb)]);
                acc[cb] = __builtin_amdgcn_mfma_f32_16x16x32_bf16(a, bb, acc[cb], 0, 0, 0);
            }
        }
    };

    stage_load(0);
    stage_write(lds[0]);
    __syncthreads();
    for (int tt = 0; tt < NT; ++tt) {
        const int cur = tt & 1;
        const bool more = (tt + 1 < NT);
        if (more) stage_load(tt + 1);         // issue early
        compute(lds[cur]);                    // 8 MFMA + 12 ds_read_b128
        if (more) stage_write(lds[cur ^ 1]);  // write late
        __syncthreads();
    }

    // C/D layout: col = lane&15, row = (lane>>4)*4 + reg
    float* gp = gram_part + (size_t)(c * NB_ + b) * (NN_ * NN_);
#pragma unroll
    for (int cb = 0; cb < 2; ++cb)
#pragma unroll
        for (int r = 0; r < 4; ++r) {
            const int i = (wr << 4) + ((l >> 4) << 2) + r;
            const int j = ((2 * wc + cb) << 4) + (l & 15);
            gp[i * NN_ + j] = acc[cb][r];
        }
    // row-sums: 32 lanes (lk4) share each staging row; reduce within 32-lane halves
#pragma unroll
    for (int p = 0; p < 4; ++p) {
        float v = sreg[p];
        v += __shfl_xor(v, 1, 64);
        v += __shfl_xor(v, 2, 64);
        v += __shfl_xor(v, 4, 64);
        v += __shfl_xor(v, 8, 64);
        v += __shfl_xor(v, 16, 64);
        if ((l & 31) == 0)
            s_part[(size_t)c * (NB_ * NN_) + b * NN_ + (lrow + 16 * p)] = v;
    }
}

// Epilogue stage 1 (round-5/8 proven; NO cross-block atomics): per (b, ijc),
// reduce gram partials over c (coalesced), reduce s_part over c into LDS,
// write wq = g/min(si,sj).
__global__ __launch_bounds__(256) void cr_weight_kernel(const float* __restrict__ gram_part,
                                                        const float* __restrict__ s_part,
                                                        float* __restrict__ wq, int NC) {
    __shared__ float s_loc[NN_];
    const int b = blockIdx.x;                        // 0..31
    if (threadIdx.x < NN_) {
        float v = 0.f;
        for (int c = 0; c < NC; ++c)
            v += s_part[(size_t)c * (NB_ * NN_) + b * NN_ + threadIdx.x];
        s_loc[threadIdx.x] = v;
    }
    __syncthreads();
    const int ij = blockIdx.y * 256 + threadIdx.x;   // 0..4095
    float g = 0.f;
#pragma unroll 8
    for (int c = 0; c < NC; ++c)
        g += gram_part[(size_t)(c * NB_ + b) * (NN_ * NN_) + ij];
    const int i = ij >> 6, j = ij & 63;
    wq[(size_t)b * (NN_ * NN_) + ij] = g / fminf(s_loc[i], s_loc[j]);
}

// Epilogue stage 2 (round-5/8 proven; final fused via last-block-done, only
// 16 RMWs total — the 512-RMW single-kernel fusion cost ~10 us in r6/r7
// from per-producer agent-scope L2 flushes).
__global__ __launch_bounds__(256) void loss2_kernel(const float* __restrict__ wq,
                                                    const int* __restrict__ nodes,
                                                    float* __restrict__ num_part,
                                                    float* __restrict__ den_part,
                                                    unsigned int* __restrict__ counter,
                                                    float* __restrict__ out) {
    __shared__ float red[8];
    __shared__ int is_last;
    const int ij = blockIdx.x * 256 + threadIdx.x;
    float acc = 0.f;
#pragma unroll
    for (int b = 0; b < NB_; ++b)
        acc += wq[(size_t)b * (NN_ * NN_) + ij];
    const float cr = acc * (1.0f / NB_);

    const int i = ij >> 6, j = ij & 63;
    const int ni = nodes[i];
    const int nj = nodes[j];
    const int ti = (ni < 7) ? 0 : ((ni < 9) ? 1 : 2);
    const int tj = (nj < 7) ? 0 : ((nj < 9) ? 1 : 2);
    const bool has_f = (ti == 1) || (tj == 1);
    const bool has_a = (ti == 2) || (tj == 2);
    const bool include = !(has_f && !has_a);
    const float beta = ((ti == 2) != (tj == 2)) ? 1.f : 0.f;
    const float wgt = (include && (j > i)) ? 1.f : 0.f;

    float num = wgt * fabsf(beta - cr);
    float den = wgt;
#pragma unroll
    for (int off = 32; off >= 1; off >>= 1) {
        num += __shfl_xor(num, off, 64);
        den += __shfl_xor(den, off, 64);
    }
    const int wave = threadIdx.x >> 6;
    const int lane = threadIdx.x & 63;
    if (lane == 0) { red[wave] = num; red[4 + wave] = den; }
    __syncthreads();
    if (threadIdx.x == 0) {
        const float bn = red[0] + red[1] + red[2] + red[3];
        const float bd = red[4] + red[5] + red[6] + red[7];
        __hip_atomic_store(&num_part[blockIdx.x], bn, __ATOMIC_RELAXED, __HIP_MEMORY_SCOPE_AGENT);
        __hip_atomic_store(&den_part[blockIdx.x], bd, __ATOMIC_RELAXED, __HIP_MEMORY_SCOPE_AGENT);
        const unsigned old = __hip_atomic_fetch_add(counter, 1u, __ATOMIC_ACQ_REL,
                                                    __HIP_MEMORY_SCOPE_AGENT);
        is_last = (old == (unsigned)(gridDim.x - 1));
    }
    __syncthreads();
    if (is_last && threadIdx.x < 64) {
        const int t = threadIdx.x;
        float n16 = 0.f, d16 = 0.f;
        if (t < 16) {
            n16 = __hip_atomic_load(&num_part[t], __ATOMIC_RELAXED, __HIP_MEMORY_SCOPE_AGENT);
            d16 = __hip_atomic_load(&den_part[t], __ATOMIC_RELAXED, __HIP_MEMORY_SCOPE_AGENT);
        }
#pragma unroll
        for (int off = 8; off >= 1; off >>= 1) {
            n16 += __shfl_xor(n16, off, 64);
            d16 += __shfl_xor(d16, off, 64);
        }
        if (t == 0) out[0] = n16 / d16;
    }
}

extern "C" void kernel_launch(void* const* d_in, const int* in_sizes, int n_in,
                              void* d_out, int out_size, void* d_ws, size_t ws_size,
                              hipStream_t stream) {
    const float* masks = (const float*)d_in[0];
    const int* nodes = (const int*)d_in[1];   // harness passes integers as int32
    float* out = (float*)d_out;

    const size_t ws_floats = ws_size / sizeof(float);
    int NC = 16;   // proven optimum (r10: NC=32 regressed)
    while (NC > 1) {
        const size_t need = (size_t)NC * NB_ * NN_ * NN_   // gram partials
                          + (size_t)NC * NB_ * NN_         // s partials
                          + (size_t)NB_ * NN_ * NN_        // wq
                          + 2 * 16 + 1;                    // partials + counter
        if (need <= ws_floats) break;
        NC >>= 1;
    }
    const int KC = HW_ / NC;   // 1024 at NC=16 -> NT=8 tiles of BK=128

    float* gram_part = (float*)d_ws;
    float* s_part    = gram_part + (size_t)NC * NB_ * NN_ * NN_;
    float* wq        = s_part    + (size_t)NC * NB_ * NN_;
    float* num_part  = wq        + (size_t)NB_ * NN_ * NN_;
    float* den_part  = num_part  + 16;
    unsigned int* counter = (unsigned int*)(den_part + 16);

    gram_kernel<<<NB_ * NC, 512, 0, stream>>>(masks, gram_part, s_part, counter, NC, KC);
    cr_weight_kernel<<<dim3(NB_, (NN_ * NN_) / 256), 256, 0, stream>>>(gram_part, s_part, wq, NC);
    loss2_kernel<<<(NN_ * NN_) / 256, 256, 0, stream>>>(wq, nodes, num_part, den_part, counter, out);
}

// Round 14
// 37.602 us; speedup vs baseline: 1.0208x; 1.0208x over previous
//
#include <hip/hip_runtime.h>
#include <cstdint>
#include <cstddef>

static constexpr int HW_ = 16384;  // h*w
static constexpr int NB_ = 32;     // batch
static constexpr int NN_ = 64;     // n
static constexpr int BK_ = 64;     // k per staged LDS tile

typedef short bfrag  __attribute__((ext_vector_type(8)));  // 8 bf16 (4 VGPRs)
typedef float f32x4  __attribute__((ext_vector_type(4)));  // MFMA accumulator

// fp32 -> bf16, round-to-nearest-even
__device__ __forceinline__ unsigned short f2bf_rne(float x) {
    unsigned u = __builtin_bit_cast(unsigned, x);
    return (unsigned short)((u + 0x7FFFu + ((u >> 16) & 1u)) >> 16);
}

// XOR-swizzled bf16-element index in a row-major [64][BK_=64] bf16 tile
// (128 B rows). byte ^= (row&7)<<4. Same involution on write+read.
__device__ __forceinline__ int swz(int row, int k) {
    int byte = (row << 7) + (k << 1);
    byte ^= (row & 7) << 4;
    return byte >> 1;
}

// r14 = r8 exactly: the proven optimum. A/B ledger on this base:
//   r9  BK=128/256t        -1.9us   r10 NC=32  -6.2us
//   r11 2-deep staging      null    r12 counted-vmcnt barrier  null
//   r13 granule 512B/512t  -0.8us
// => gram is at its access-pattern BW roofline (~5.2-6 TB/s for 256B
// granules at 64KB row stride); scheduling levers exhausted.
__global__ __launch_bounds__(256) void gram_kernel(const float* __restrict__ masks,
                                                   float* __restrict__ gram_part,
                                                   float* __restrict__ s_part,
                                                   unsigned int* __restrict__ counter,
                                                   int NC, int KC) {
    // zero loss2's sync counter (stream-ordered; kills the memset dispatch)
    if (blockIdx.x == 0 && threadIdx.x == 0) *counter = 0u;

    __shared__ __align__(16) unsigned short lds[2][NN_ * BK_];  // 2 x 8 KiB bf16
    const int bx = blockIdx.x;
    const int b  = bx / NC;
    const int c  = bx - b * NC;
    const int t  = threadIdx.x;        // 256 threads = 4 waves
    const int l  = t & 63;
    const int w  = t >> 6;             // wave id: owns output rows [16w,16w+16)
    const int lrow = t >> 4;           // staging row base 0..15
    const int lk4  = t & 15;           // staging float4 index along k
    const float* mb = masks + (size_t)b * (NN_ * HW_) + (size_t)c * KC;
    const int NT = KC / BK_;

    f32x4 acc[4];
#pragma unroll
    for (int cb = 0; cb < 4; ++cb) acc[cb] = (f32x4){0.f, 0.f, 0.f, 0.f};
    float sreg[4] = {0.f, 0.f, 0.f, 0.f};
    float4 ld[4];

    auto stage_load = [&](int tt) {
        const float* src = mb + tt * BK_ + lk4 * 4;
#pragma unroll
        for (int p = 0; p < 4; ++p)
            ld[p] = *reinterpret_cast<const float4*>(src + (size_t)(lrow + 16 * p) * HW_);
    };
    auto stage_write = [&](unsigned short* buf) {
#pragma unroll
        for (int p = 0; p < 4; ++p) {
            const float m0 = fmaxf(0.f, (ld[p].x + 1.f) * 0.5f);
            const float m1 = fmaxf(0.f, (ld[p].y + 1.f) * 0.5f);
            const float m2 = fmaxf(0.f, (ld[p].z + 1.f) * 0.5f);
            const float m3 = fmaxf(0.f, (ld[p].w + 1.f) * 0.5f);
            sreg[p] += (m0 + m1) + (m2 + m3);
            const ushort4 pk = make_ushort4(f2bf_rne(m0), f2bf_rne(m1),
                                            f2bf_rne(m2), f2bf_rne(m3));
            *reinterpret_cast<ushort4*>(&buf[swz(lrow + 16 * p, lk4 * 4)]) = pk;
        }
    };
    auto compute = [&](const unsigned short* buf) {
#pragma unroll
        for (int ks = 0; ks < BK_; ks += 32) {
            const int kb = ks + ((l >> 4) << 3);
            const bfrag a = *reinterpret_cast<const bfrag*>(&buf[swz((w << 4) + (l & 15), kb)]);
#pragma unroll
            for (int cb = 0; cb < 4; ++cb) {
                const bfrag bb = *reinterpret_cast<const bfrag*>(&buf[swz((cb << 4) + (l & 15), kb)]);
                acc[cb] = __builtin_amdgcn_mfma_f32_16x16x32_bf16(a, bb, acc[cb], 0, 0, 0);
            }
        }
    };

    stage_load(0);
    stage_write(lds[0]);
    __syncthreads();
    for (int tt = 0; tt < NT; ++tt) {
        const int cur = tt & 1;
        const bool more = (tt + 1 < NT);
        if (more) stage_load(tt + 1);         // issue early
        compute(lds[cur]);                    // hide HBM latency under MFMA
        if (more) stage_write(lds[cur ^ 1]);  // write late
        __syncthreads();
    }

    // C/D layout: col = lane&15, row = (lane>>4)*4 + reg
    float* gp = gram_part + (size_t)(c * NB_ + b) * (NN_ * NN_);
#pragma unroll
    for (int cb = 0; cb < 4; ++cb)
#pragma unroll
        for (int r = 0; r < 4; ++r) {
            const int i = (w << 4) + ((l >> 4) << 2) + r;
            const int j = (cb << 4) + (l & 15);
            gp[i * NN_ + j] = acc[cb][r];
        }
#pragma unroll
    for (int p = 0; p < 4; ++p) {
        float v = sreg[p];
        v += __shfl_xor(v, 1, 64);
        v += __shfl_xor(v, 2, 64);
        v += __shfl_xor(v, 4, 64);
        v += __shfl_xor(v, 8, 64);
        if ((l & 15) == 0)
            s_part[(size_t)c * (NB_ * NN_) + b * NN_ + (lrow + 16 * p)] = v;
    }
}

// Epilogue stage 1 (proven; NO cross-block atomics): per (b, ijc), reduce
// gram partials over c (coalesced), reduce s_part over c into LDS,
// write wq = g/min(si,sj).
__global__ __launch_bounds__(256) void cr_weight_kernel(const float* __restrict__ gram_part,
                                                        const float* __restrict__ s_part,
                                                        float* __restrict__ wq, int NC) {
    __shared__ float s_loc[NN_];
    const int b = blockIdx.x;                        // 0..31
    if (threadIdx.x < NN_) {
        float v = 0.f;
        for (int c = 0; c < NC; ++c)
            v += s_part[(size_t)c * (NB_ * NN_) + b * NN_ + threadIdx.x];
        s_loc[threadIdx.x] = v;
    }
    __syncthreads();
    const int ij = blockIdx.y * 256 + threadIdx.x;   // 0..4095
    float g = 0.f;
#pragma unroll 8
    for (int c = 0; c < NC; ++c)
        g += gram_part[(size_t)(c * NB_ + b) * (NN_ * NN_) + ij];
    const int i = ij >> 6, j = ij & 63;
    wq[(size_t)b * (NN_ * NN_) + ij] = g / fminf(s_loc[i], s_loc[j]);
}

// Epilogue stage 2 (proven; final fused via last-block-done, only 16 RMWs
// total — the 512-RMW single-kernel fusion cost ~10 us in r6/r7 from
// per-producer agent-scope L2 flushes).
__global__ __launch_bounds__(256) void loss2_kernel(const float* __restrict__ wq,
                                                    const int* __restrict__ nodes,
                                                    float* __restrict__ num_part,
                                                    float* __restrict__ den_part,
                                                    unsigned int* __restrict__ counter,
                                                    float* __restrict__ out) {
    __shared__ float red[8];
    __shared__ int is_last;
    const int ij = blockIdx.x * 256 + threadIdx.x;
    float acc = 0.f;
#pragma unroll
    for (int b = 0; b < NB_; ++b)
        acc += wq[(size_t)b * (NN_ * NN_) + ij];
    const float cr = acc * (1.0f / NB_);

    const int i = ij >> 6, j = ij & 63;
    const int ni = nodes[i];
    const int nj = nodes[j];
    const int ti = (ni < 7) ? 0 : ((ni < 9) ? 1 : 2);
    const int tj = (nj < 7) ? 0 : ((nj < 9) ? 1 : 2);
    const bool has_f = (ti == 1) || (tj == 1);
    const bool has_a = (ti == 2) || (tj == 2);
    const bool include = !(has_f && !has_a);
    const float beta = ((ti == 2) != (tj == 2)) ? 1.f : 0.f;
    const float wgt = (include && (j > i)) ? 1.f : 0.f;

    float num = wgt * fabsf(beta - cr);
    float den = wgt;
#pragma unroll
    for (int off = 32; off >= 1; off >>= 1) {
        num += __shfl_xor(num, off, 64);
        den += __shfl_xor(den, off, 64);
    }
    const int wave = threadIdx.x >> 6;
    const int lane = threadIdx.x & 63;
    if (lane == 0) { red[wave] = num; red[4 + wave] = den; }
    __syncthreads();
    if (threadIdx.x == 0) {
        const float bn = red[0] + red[1] + red[2] + red[3];
        const float bd = red[4] + red[5] + red[6] + red[7];
        __hip_atomic_store(&num_part[blockIdx.x], bn, __ATOMIC_RELAXED, __HIP_MEMORY_SCOPE_AGENT);
        __hip_atomic_store(&den_part[blockIdx.x], bd, __ATOMIC_RELAXED, __HIP_MEMORY_SCOPE_AGENT);
        const unsigned old = __hip_atomic_fetch_add(counter, 1u, __ATOMIC_ACQ_REL,
                                                    __HIP_MEMORY_SCOPE_AGENT);
        is_last = (old == (unsigned)(gridDim.x - 1));
    }
    __syncthreads();
    if (is_last && threadIdx.x < 64) {
        const int t = threadIdx.x;
        float n16 = 0.f, d16 = 0.f;
        if (t < 16) {
            n16 = __hip_atomic_load(&num_part[t], __ATOMIC_RELAXED, __HIP_MEMORY_SCOPE_AGENT);
            d16 = __hip_atomic_load(&den_part[t], __ATOMIC_RELAXED, __HIP_MEMORY_SCOPE_AGENT);
        }
#pragma unroll
        for (int off = 8; off >= 1; off >>= 1) {
            n16 += __shfl_xor(n16, off, 64);
            d16 += __shfl_xor(d16, off, 64);
        }
        if (t == 0) out[0] = n16 / d16;
    }
}

extern "C" void kernel_launch(void* const* d_in, const int* in_sizes, int n_in,
                              void* d_out, int out_size, void* d_ws, size_t ws_size,
                              hipStream_t stream) {
    const float* masks = (const float*)d_in[0];
    const int* nodes = (const int*)d_in[1];   // harness passes integers as int32
    float* out = (float*)d_out;

    const size_t ws_floats = ws_size / sizeof(float);
    int NC = 16;   // proven optimum (r10: NC=32 regressed)
    while (NC > 1) {
        const size_t need = (size_t)NC * NB_ * NN_ * NN_   // gram partials
                          + (size_t)NC * NB_ * NN_         // s partials
                          + (size_t)NB_ * NN_ * NN_        // wq
                          + 2 * 16 + 1;                    // partials + counter
        if (need <= ws_floats) break;
        NC >>= 1;
    }
    const int KC = HW_ / NC;

    float* gram_part = (float*)d_ws;
    float* s_part    = gram_part + (size_t)NC * NB_ * NN_ * NN_;
    float* wq        = s_part    + (size_t)NC * NB_ * NN_;
    float* num_part  = wq        + (size_t)NB_ * NN_ * NN_;
    float* den_part  = num_part  + 16;
    unsigned int* counter = (unsigned int*)(den_part + 16);

    gram_kernel<<<NB_ * NC, 256, 0, stream>>>(masks, gram_part, s_part, counter, NC, KC);
    cr_weight_kernel<<<dim3(NB_, (NN_ * NN_) / 256), 256, 0, stream>>>(gram_part, s_part, wq, NC);
    loss2_kernel<<<(NN_ * NN_) / 256, 256, 0, stream>>>(wq, nodes, num_part, den_part, counter, out);
}